// Round 2
// baseline (2058.299 us; speedup 1.0000x reference)
//
#include <hip/hip_runtime.h>
#include <hip/hip_bf16.h>
#include <cstdint>
#include <cstddef>

// Inputs fp32 (per reference setup_inputs), output fp32. Internal bf16 MFMA.

#define S_ 2048
#define B_ 4
#define H_ 2048
#define F_ 1408
#define F2_ 2816
#define E_ 8
#define T_ 8192

typedef float f32x4 __attribute__((ext_vector_type(4)));
typedef short s16x8 __attribute__((ext_vector_type(8)));

__device__ __forceinline__ unsigned short f2b(float f) {
  union { unsigned int i; float f; } v; v.f = f;
  unsigned int r = v.i + 0x7FFFu + ((v.i >> 16) & 1u);
  return (unsigned short)(r >> 16);
}
__device__ __forceinline__ unsigned int pkbf(float lo, float hi) {
  __hip_bfloat162 h2 = __float22bfloat162_rn(make_float2(lo, hi));
  union { __hip_bfloat162 v; unsigned int u; } c; c.v = h2; return c.u;
}

// ---------------- workspace layout (bytes) ----------------
// 0     : int counts[8]
// 32    : int cursor[8]
// 64    : int offs[8]
// 128   : int   eidx[2T]       (65536)
// 65664 : float ewt[2T]        (65536)
// 131200: int   rowlist[2T]    (65536)
// 196736: float rowwt[2T]      (65536)
// 262272: bf16  g[2T][F]       (46137344)  -> total ~46.4 MB

__global__ void zero_kernel(int* ws_i) {
  if (threadIdx.x < 16) ws_i[threadIdx.x] = 0;   // counts + cursor
}

// one wave per token: fp32 logits over 8 experts, softmax, top-2
__global__ __launch_bounds__(256) void gate_kernel(
    const float* __restrict__ x, const float* __restrict__ wg,
    int* __restrict__ counts, int* __restrict__ eidx, float* __restrict__ ewt) {
  int wave = threadIdx.x >> 6, lane = threadIdx.x & 63;
  int t = blockIdx.x * 4 + wave;
  int b = t >> 11, s = t & (S_ - 1);
  const float* xrow = x + (size_t)(s * B_ + b) * H_;
  float acc[E_];
#pragma unroll
  for (int e = 0; e < E_; e++) acc[e] = 0.f;
  for (int h0 = lane * 4; h0 < H_; h0 += 256) {
    f32x4 xa = *(const f32x4*)(xrow + h0);
#pragma unroll
    for (int e = 0; e < E_; e++) {
      f32x4 wa = *(const f32x4*)(wg + e * H_ + h0);
      acc[e] += xa[0] * wa[0] + xa[1] * wa[1] + xa[2] * wa[2] + xa[3] * wa[3];
    }
  }
#pragma unroll
  for (int e = 0; e < E_; e++)
    for (int off = 32; off; off >>= 1) acc[e] += __shfl_xor(acc[e], off, 64);
  if (lane == 0) {
    float m = acc[0];
#pragma unroll
    for (int e = 1; e < E_; e++) m = fmaxf(m, acc[e]);
    float ex[E_], ssum = 0.f;
#pragma unroll
    for (int e = 0; e < E_; e++) { ex[e] = __expf(acc[e] - m); ssum += ex[e]; }
    float sc[E_];
#pragma unroll
    for (int e = 0; e < E_; e++) sc[e] = ex[e] / ssum;
    int i1 = 0;
#pragma unroll
    for (int e = 1; e < E_; e++) if (sc[e] > sc[i1]) i1 = e;
    int i2 = (i1 == 0) ? 1 : 0;
#pragma unroll
    for (int e = 0; e < E_; e++) if (e != i1 && sc[e] > sc[i2]) i2 = e;
    float wsum = sc[i1] + sc[i2] + 1e-20f;
    eidx[2 * t] = i1;     ewt[2 * t] = sc[i1] / wsum;
    eidx[2 * t + 1] = i2; ewt[2 * t + 1] = sc[i2] / wsum;
    atomicAdd(&counts[i1], 1);
    atomicAdd(&counts[i2], 1);
  }
}

__global__ void scan_kernel(const int* __restrict__ counts, int* __restrict__ offs) {
  if (threadIdx.x == 0) {
    int run = 0;
    for (int e = 0; e < E_; e++) { offs[e] = run; run += counts[e]; }
  }
}

__global__ void assign_kernel(const int* __restrict__ eidx, const float* __restrict__ ewt,
                              const int* __restrict__ offs, int* __restrict__ cursor,
                              int* __restrict__ rowlist, float* __restrict__ rowwt) {
  int t = blockIdx.x * 256 + threadIdx.x;
  if (t >= T_) return;
#pragma unroll
  for (int k = 0; k < 2; k++) {
    int e = eidx[2 * t + k];
    int pos = atomicAdd(&cursor[e], 1);
    int slot = offs[e] + pos;
    rowlist[slot] = t;
    rowwt[slot] = ewt[2 * t + k];
  }
}

// GEMM1 + swiglu. grid (rt=64, ft=22, e=8), block 256.
// Tile: 128 rows x 64 cols, both swiglu halves. acc[half][4][2] f32x4.
__global__ __launch_bounds__(256) void gemm1_kernel(
    const float* __restrict__ x, const float* __restrict__ w1,
    const int* __restrict__ counts, const int* __restrict__ offs,
    const int* __restrict__ rowlist, unsigned short* __restrict__ g) {
  int e = blockIdx.z, ft = blockIdx.y, rt = blockIdx.x;
  int ne = counts[e];
  if (rt * 128 >= ne) return;
  int base = offs[e];

  __shared__ unsigned short aL[128 * 40];   // [row][k], stride 40
  __shared__ unsigned short bLa[64 * 40];   // [col][k]
  __shared__ unsigned short bLb[64 * 40];

  int tid = threadIdx.x;
  int lane = tid & 63, wave = tid >> 6;
  int wm = (wave & 1) * 64, wn = (wave >> 1) * 32;
  int quad = lane >> 4, l15 = lane & 15;

  // A staging: row arow, cols achunk*16..+16 (fp32 -> bf16)
  int arow = tid & 127, achunk = tid >> 7;
  int rc = min(rt * 128 + arow, ne - 1);
  int tok = rowlist[base + rc];
  const float* xrow = x + (size_t)((tok & (S_ - 1)) * B_ + (tok >> 11)) * H_ + achunk * 16;

  // B staging: half hs; cols bc*4..+4, k rows bq*4..+4
  int hs = tid >> 7, bt = tid & 127;
  int bc = bt & 15, bq = bt >> 4;
  const float* wsrc = w1 + (size_t)e * H_ * F2_ + (hs ? F_ : 0) + ft * 64 + bc * 4;
  unsigned short* bdst = hs ? bLb : bLa;

  f32x4 acc[2][4][2];
#pragma unroll
  for (int h2 = 0; h2 < 2; h2++)
    for (int i = 0; i < 4; i++)
      for (int j = 0; j < 2; j++) acc[h2][i][j] = (f32x4){0.f, 0.f, 0.f, 0.f};

  for (int k0 = 0; k0 < H_; k0 += 32) {
    f32x4 av0 = *(const f32x4*)(xrow + k0);
    f32x4 av1 = *(const f32x4*)(xrow + k0 + 4);
    f32x4 av2 = *(const f32x4*)(xrow + k0 + 8);
    f32x4 av3 = *(const f32x4*)(xrow + k0 + 12);
    const float* wk = wsrc + (size_t)(k0 + bq * 4) * F2_;
    f32x4 bv0 = *(const f32x4*)(wk);
    f32x4 bv1 = *(const f32x4*)(wk + F2_);
    f32x4 bv2 = *(const f32x4*)(wk + 2 * F2_);
    f32x4 bv3 = *(const f32x4*)(wk + 3 * F2_);
    __syncthreads();  // prior iteration's LDS reads done
    {
      uint4 u0, u1;
      u0.x = pkbf(av0[0], av0[1]); u0.y = pkbf(av0[2], av0[3]);
      u0.z = pkbf(av1[0], av1[1]); u0.w = pkbf(av1[2], av1[3]);
      u1.x = pkbf(av2[0], av2[1]); u1.y = pkbf(av2[2], av2[3]);
      u1.z = pkbf(av3[0], av3[1]); u1.w = pkbf(av3[2], av3[3]);
      *(uint4*)&aL[arow * 40 + achunk * 16] = u0;
      *(uint4*)&aL[arow * 40 + achunk * 16 + 8] = u1;
    }
#pragma unroll
    for (int j = 0; j < 4; j++) {
      uint2 wv;
      wv.x = pkbf(bv0[j], bv1[j]);
      wv.y = pkbf(bv2[j], bv3[j]);
      *(uint2*)&bdst[(bc * 4 + j) * 40 + bq * 4] = wv;
    }
    __syncthreads();

    s16x8 af[4];
#pragma unroll
    for (int mi = 0; mi < 4; mi++)
      af[mi] = *(const s16x8*)&aL[(wm + mi * 16 + l15) * 40 + quad * 8];
    s16x8 bfa[2], bfb[2];
#pragma unroll
    for (int ni = 0; ni < 2; ni++) {
      bfa[ni] = *(const s16x8*)&bLa[(wn + ni * 16 + l15) * 40 + quad * 8];
      bfb[ni] = *(const s16x8*)&bLb[(wn + ni * 16 + l15) * 40 + quad * 8];
    }
#pragma unroll
    for (int mi = 0; mi < 4; mi++)
#pragma unroll
      for (int ni = 0; ni < 2; ni++) {
        acc[0][mi][ni] = __builtin_amdgcn_mfma_f32_16x16x32_bf16(af[mi], bfa[ni], acc[0][mi][ni], 0, 0, 0);
        acc[1][mi][ni] = __builtin_amdgcn_mfma_f32_16x16x32_bf16(af[mi], bfb[ni], acc[1][mi][ni], 0, 0, 0);
      }
  }

#pragma unroll
  for (int mi = 0; mi < 4; mi++)
#pragma unroll
    for (int ni = 0; ni < 2; ni++)
#pragma unroll
      for (int v = 0; v < 4; v++) {
        int row = wm + mi * 16 + quad * 4 + v;
        if (rt * 128 + row < ne) {
          int col = wn + ni * 16 + l15;
          float a = acc[0][mi][ni][v], bb = acc[1][mi][ni][v];
          float sg = a / (1.f + __expf(-a));
          g[(size_t)(base + rt * 128 + row) * F_ + ft * 64 + col] = f2b(sg * bb);
        }
      }
}

// GEMM2: out[token, n] += rowwt * (g[slot,:] @ W2[e]).  grid (64, 16, 8).
__global__ __launch_bounds__(256) void gemm2_kernel(
    const unsigned short* __restrict__ g, const float* __restrict__ w2,
    const int* __restrict__ counts, const int* __restrict__ offs,
    const int* __restrict__ rowlist, const float* __restrict__ rowwt,
    float* __restrict__ out) {
  int e = blockIdx.z, nt = blockIdx.y, rt = blockIdx.x;
  int ne = counts[e];
  if (rt * 128 >= ne) return;
  int base = offs[e];

  __shared__ unsigned short aL[128 * 40];   // [row][k]
  __shared__ unsigned short bL[128 * 40];   // [col][k]
  __shared__ float rwL[128];
  __shared__ int   toL[128];

  int tid = threadIdx.x;
  int lane = tid & 63, wave = tid >> 6;
  int wm = (wave & 1) * 64, wn = (wave >> 1) * 64;
  int quad = lane >> 4, l15 = lane & 15;

  int arow = tid & 127, achunk = tid >> 7;
  int rc = min(rt * 128 + arow, ne - 1);
  const unsigned short* grow = g + (size_t)(base + rc) * F_ + achunk * 16;

  int bc = tid & 31, bq = tid >> 5;
  const float* wsrc = w2 + (size_t)e * F_ * H_ + nt * 128 + bc * 4;

  if (tid < 128) {
    int rr = min(rt * 128 + tid, ne - 1);
    rwL[tid] = rowwt[base + rr];
    int tk = rowlist[base + rr];
    toL[tid] = ((tk & (S_ - 1)) * B_ + (tk >> 11)) * H_;
  }

  f32x4 acc[4][4];
#pragma unroll
  for (int i = 0; i < 4; i++)
    for (int j = 0; j < 4; j++) acc[i][j] = (f32x4){0.f, 0.f, 0.f, 0.f};

  for (int k0 = 0; k0 < F_; k0 += 32) {
    uint4 v0 = *(const uint4*)(grow + k0);
    uint4 v1 = *(const uint4*)(grow + k0 + 8);
    const float* wk = wsrc + (size_t)(k0 + bq * 4) * H_;
    f32x4 bv0 = *(const f32x4*)(wk);
    f32x4 bv1 = *(const f32x4*)(wk + H_);
    f32x4 bv2 = *(const f32x4*)(wk + 2 * H_);
    f32x4 bv3 = *(const f32x4*)(wk + 3 * H_);
    __syncthreads();
    *(uint4*)&aL[arow * 40 + achunk * 16] = v0;
    *(uint4*)&aL[arow * 40 + achunk * 16 + 8] = v1;
#pragma unroll
    for (int j = 0; j < 4; j++) {
      uint2 wv;
      wv.x = pkbf(bv0[j], bv1[j]);
      wv.y = pkbf(bv2[j], bv3[j]);
      *(uint2*)&bL[(bc * 4 + j) * 40 + bq * 4] = wv;
    }
    __syncthreads();

    s16x8 af[4];
#pragma unroll
    for (int mi = 0; mi < 4; mi++)
      af[mi] = *(const s16x8*)&aL[(wm + mi * 16 + l15) * 40 + quad * 8];
    s16x8 bf[4];
#pragma unroll
    for (int ni = 0; ni < 4; ni++)
      bf[ni] = *(const s16x8*)&bL[(wn + ni * 16 + l15) * 40 + quad * 8];
#pragma unroll
    for (int mi = 0; mi < 4; mi++)
#pragma unroll
      for (int ni = 0; ni < 4; ni++)
        acc[mi][ni] = __builtin_amdgcn_mfma_f32_16x16x32_bf16(af[mi], bf[ni], acc[mi][ni], 0, 0, 0);
  }

#pragma unroll
  for (int mi = 0; mi < 4; mi++)
#pragma unroll
    for (int ni = 0; ni < 4; ni++)
#pragma unroll
      for (int v = 0; v < 4; v++) {
        int row = wm + mi * 16 + quad * 4 + v;
        if (rt * 128 + row < ne) {
          int col = wn + ni * 16 + l15;
          atomicAdd(&out[(size_t)toL[row] + nt * 128 + col], acc[mi][ni][v] * rwL[row]);
        }
      }
}

extern "C" void kernel_launch(void* const* d_in, const int* in_sizes, int n_in,
                              void* d_out, int out_size, void* d_ws, size_t ws_size,
                              hipStream_t stream) {
  const float* x  = (const float*)d_in[0];
  const float* wg = (const float*)d_in[1];
  const float* w1 = (const float*)d_in[2];
  const float* w2 = (const float*)d_in[3];
  float* out = (float*)d_out;

  char* ws = (char*)d_ws;
  int*   counts  = (int*)(ws + 0);
  int*   cursor  = (int*)(ws + 32);
  int*   offs    = (int*)(ws + 64);
  int*   eidx    = (int*)(ws + 128);
  float* ewt     = (float*)(ws + 65664);
  int*   rowlist = (int*)(ws + 131200);
  float* rowwt   = (float*)(ws + 196736);
  unsigned short* g = (unsigned short*)(ws + 262272);

  hipMemsetAsync(d_out, 0, (size_t)out_size * sizeof(float), stream);
  zero_kernel<<<1, 64, 0, stream>>>((int*)ws);
  gate_kernel<<<T_ / 4, 256, 0, stream>>>(x, wg, counts, eidx, ewt);
  scan_kernel<<<1, 64, 0, stream>>>(counts, offs);
  assign_kernel<<<T_ / 256, 256, 0, stream>>>(eidx, ewt, offs, cursor, rowlist, rowwt);
  gemm1_kernel<<<dim3(64, 22, E_), 256, 0, stream>>>(x, w1, counts, offs, rowlist, g);
  gemm2_kernel<<<dim3(64, 16, E_), 256, 0, stream>>>(g, w2, counts, offs, rowlist, rowwt, out);
}

// Round 3
// 1414.151 us; speedup vs baseline: 1.4555x; 1.4555x over previous
//
#include <hip/hip_runtime.h>
#include <hip/hip_bf16.h>
#include <cstdint>
#include <cstddef>

// Inputs fp32, output fp32. Internal bf16 MFMA (m97 recipe: one-shot bf16
// convert/transpose passes, then global_load_lds-staged 128-tile GEMMs).

#define S_ 2048
#define B_ 4
#define H_ 2048
#define F_ 1408
#define F2_ 2816
#define E_ 8
#define T_ 8192

typedef float f32x4 __attribute__((ext_vector_type(4)));
typedef short s16x8 __attribute__((ext_vector_type(8)));

__device__ __forceinline__ unsigned short f2b(float f) {
  union { unsigned int i; float f; } v; v.f = f;
  unsigned int r = v.i + 0x7FFFu + ((v.i >> 16) & 1u);
  return (unsigned short)(r >> 16);
}
__device__ __forceinline__ unsigned int pkbf(float lo, float hi) {
  __hip_bfloat162 h2 = __float22bfloat162_rn(make_float2(lo, hi));
  union { __hip_bfloat162 v; unsigned int u; } c; c.v = h2; return c.u;
}
__device__ __forceinline__ void gld16(const unsigned short* gp, unsigned short* lp) {
  __builtin_amdgcn_global_load_lds(
      (const __attribute__((address_space(1))) unsigned int*)gp,
      (__attribute__((address_space(3))) unsigned int*)lp, 16, 0, 0);
}

// ---------------- workspace layout (bytes) ----------------
// 0       : int counts[8]; 32: cursor[8]; 64: offs[8]
// 128     : int   eidx[2T]
// 65664   : float ewt[2T]
// 131200  : int   rowlist[2T]
// 196736  : float rowwt[2T]
// 262272  : bf16  g[2T][F]            (46137344)
// 46399616: bf16  xb[T][H]            (33554432)   x cast, token layout
// 79954048: bf16  w1t[E][2F][H]       (92274688)   transposed (k-major)
// 172228736: bf16 w2t[E][H][F]        (46137344)   transposed (k-major)
// total ~218.4 MB

__global__ void zero_kernel(int* ws_i) {
  if (threadIdx.x < 16) ws_i[threadIdx.x] = 0;
}

__global__ __launch_bounds__(256) void cvt_kernel(
    const float* __restrict__ src, unsigned short* __restrict__ dst, int n8) {
  int i = blockIdx.x * 256 + threadIdx.x;
  if (i >= n8) return;
  f32x4 a = *(const f32x4*)(src + (size_t)i * 8);
  f32x4 b = *(const f32x4*)(src + (size_t)i * 8 + 4);
  uint4 u;
  u.x = pkbf(a[0], a[1]); u.y = pkbf(a[2], a[3]);
  u.z = pkbf(b[0], b[1]); u.w = pkbf(b[2], b[3]);
  *(uint4*)(dst + (size_t)i * 8) = u;
}

// src[e][r][c] fp32 -> dst[e][c][r] bf16.  64x64 tiles, dims % 64 == 0.
__global__ __launch_bounds__(256) void tcvt_kernel(
    const float* __restrict__ src, unsigned short* __restrict__ dst,
    int rows, int cols) {
  int e = blockIdx.z;
  int c0 = blockIdx.x * 64, r0 = blockIdx.y * 64;
  const float* s = src + (size_t)e * rows * cols;
  unsigned short* d = dst + (size_t)e * rows * cols;
  __shared__ unsigned short Lt[64][72];
  int tid = threadIdx.x;
  int cl = tid & 63, w = tid >> 6;
#pragma unroll
  for (int i = 0; i < 16; i++) {
    int r = w * 16 + i;
    Lt[cl][r] = f2b(s[(size_t)(r0 + r) * cols + c0 + cl]);
  }
  __syncthreads();
  int cc = tid >> 3, hc = tid & 7;
#pragma unroll
  for (int j = 0; j < 2; j++) {
    int c = cc + j * 32;
    *(uint4*)&d[(size_t)(c0 + c) * rows + r0 + hc * 8] = *(uint4*)&Lt[c][hc * 8];
  }
}

// one wave per token: fp32 logits over 8 experts, softmax, top-2
__global__ __launch_bounds__(256) void gate_kernel(
    const float* __restrict__ x, const float* __restrict__ wg,
    int* __restrict__ counts, int* __restrict__ eidx, float* __restrict__ ewt) {
  int wave = threadIdx.x >> 6, lane = threadIdx.x & 63;
  int t = blockIdx.x * 4 + wave;
  int b = t >> 11, s = t & (S_ - 1);
  const float* xrow = x + (size_t)(s * B_ + b) * H_;
  float acc[E_];
#pragma unroll
  for (int e = 0; e < E_; e++) acc[e] = 0.f;
  for (int h0 = lane * 4; h0 < H_; h0 += 256) {
    f32x4 xa = *(const f32x4*)(xrow + h0);
#pragma unroll
    for (int e = 0; e < E_; e++) {
      f32x4 wa = *(const f32x4*)(wg + e * H_ + h0);
      acc[e] += xa[0] * wa[0] + xa[1] * wa[1] + xa[2] * wa[2] + xa[3] * wa[3];
    }
  }
#pragma unroll
  for (int e = 0; e < E_; e++)
    for (int off = 32; off; off >>= 1) acc[e] += __shfl_xor(acc[e], off, 64);
  if (lane == 0) {
    float m = acc[0];
#pragma unroll
    for (int e = 1; e < E_; e++) m = fmaxf(m, acc[e]);
    float ex[E_], ssum = 0.f;
#pragma unroll
    for (int e = 0; e < E_; e++) { ex[e] = __expf(acc[e] - m); ssum += ex[e]; }
    float sc[E_];
#pragma unroll
    for (int e = 0; e < E_; e++) sc[e] = ex[e] / ssum;
    int i1 = 0;
#pragma unroll
    for (int e = 1; e < E_; e++) if (sc[e] > sc[i1]) i1 = e;
    int i2 = (i1 == 0) ? 1 : 0;
#pragma unroll
    for (int e = 0; e < E_; e++) if (e != i1 && sc[e] > sc[i2]) i2 = e;
    float wsum = sc[i1] + sc[i2] + 1e-20f;
    eidx[2 * t] = i1;     ewt[2 * t] = sc[i1] / wsum;
    eidx[2 * t + 1] = i2; ewt[2 * t + 1] = sc[i2] / wsum;
    atomicAdd(&counts[i1], 1);
    atomicAdd(&counts[i2], 1);
  }
}

__global__ void scan_kernel(const int* __restrict__ counts, int* __restrict__ offs) {
  if (threadIdx.x == 0) {
    int run = 0;
    for (int e = 0; e < E_; e++) { offs[e] = run; run += counts[e]; }
  }
}

__global__ void assign_kernel(const int* __restrict__ eidx, const float* __restrict__ ewt,
                              const int* __restrict__ offs, int* __restrict__ cursor,
                              int* __restrict__ rowlist, float* __restrict__ rowwt) {
  int t = blockIdx.x * 256 + threadIdx.x;
  if (t >= T_) return;
#pragma unroll
  for (int k = 0; k < 2; k++) {
    int e = eidx[2 * t + k];
    int pos = atomicAdd(&cursor[e], 1);
    int slot = offs[e] + pos;
    rowlist[slot] = t;
    rowwt[slot] = ewt[2 * t + k];
  }
}

// GEMM1 + swiglu. grid (rt=64, ft=22, e=8). Tile 128 rows x 64 f-pairs, BK=32.
__global__ __launch_bounds__(256) void gemm1_kernel(
    const unsigned short* __restrict__ xb, const unsigned short* __restrict__ w1t,
    const int* __restrict__ counts, const int* __restrict__ offs,
    const int* __restrict__ rowlist, unsigned short* __restrict__ g) {
  int e = blockIdx.z, ft = blockIdx.y, rt = blockIdx.x;
  int ne = counts[e];
  if (rt * 128 >= ne) return;
  int base = offs[e];

  __shared__ unsigned short aL[128 * 32];
  __shared__ unsigned short bLa[64 * 32];
  __shared__ unsigned short bLb[64 * 32];

  int tid = threadIdx.x;
  int lane = tid & 63, wave = tid >> 6;
  int wm = (wave & 1) * 64, wn = (wave >> 1) * 32;
  int quad = lane >> 4, l15 = lane & 15;

  // staging: chunk layout row = tid>>2 (+64), kchunk = tid&3
  int srow = tid >> 2, kc = tid & 3;
  int t0 = rowlist[base + min(rt * 128 + srow, ne - 1)];
  int t1 = rowlist[base + min(rt * 128 + 64 + srow, ne - 1)];
  const unsigned short* ap0 = xb + (size_t)((t0 & (S_ - 1)) * B_ + (t0 >> 11)) * H_ + kc * 8;
  const unsigned short* ap1 = xb + (size_t)((t1 & (S_ - 1)) * B_ + (t1 >> 11)) * H_ + kc * 8;
  const unsigned short* bpa = w1t + ((size_t)e * F2_ + ft * 64 + srow) * H_ + kc * 8;
  const unsigned short* bpb = bpa + (size_t)F_ * H_;

  unsigned short* aD0 = aL + wave * 512;          // rows 0..63
  unsigned short* aD1 = aL + 2048 + wave * 512;   // rows 64..127
  unsigned short* bDa = bLa + wave * 512;
  unsigned short* bDb = bLb + wave * 512;

  f32x4 acc[2][4][2];
#pragma unroll
  for (int h2 = 0; h2 < 2; h2++)
    for (int i = 0; i < 4; i++)
      for (int j = 0; j < 2; j++) acc[h2][i][j] = (f32x4){0.f, 0.f, 0.f, 0.f};

  for (int k0 = 0; k0 < H_; k0 += 32) {
    __syncthreads();                 // all waves done reading previous tile
    gld16(ap0 + k0, aD0);
    gld16(ap1 + k0, aD1);
    gld16(bpa + k0, bDa);
    gld16(bpb + k0, bDb);
    __syncthreads();                 // vmcnt(0) drain -> tile complete

    s16x8 af[4];
#pragma unroll
    for (int mi = 0; mi < 4; mi++)
      af[mi] = *(const s16x8*)&aL[(wm + mi * 16 + l15) * 32 + quad * 8];
    s16x8 bfa[2], bfb[2];
#pragma unroll
    for (int ni = 0; ni < 2; ni++) {
      bfa[ni] = *(const s16x8*)&bLa[(wn + ni * 16 + l15) * 32 + quad * 8];
      bfb[ni] = *(const s16x8*)&bLb[(wn + ni * 16 + l15) * 32 + quad * 8];
    }
#pragma unroll
    for (int mi = 0; mi < 4; mi++)
#pragma unroll
      for (int ni = 0; ni < 2; ni++) {
        acc[0][mi][ni] = __builtin_amdgcn_mfma_f32_16x16x32_bf16(af[mi], bfa[ni], acc[0][mi][ni], 0, 0, 0);
        acc[1][mi][ni] = __builtin_amdgcn_mfma_f32_16x16x32_bf16(af[mi], bfb[ni], acc[1][mi][ni], 0, 0, 0);
      }
  }

#pragma unroll
  for (int mi = 0; mi < 4; mi++)
#pragma unroll
    for (int ni = 0; ni < 2; ni++)
#pragma unroll
      for (int v = 0; v < 4; v++) {
        int row = wm + mi * 16 + quad * 4 + v;
        if (rt * 128 + row < ne) {
          int col = wn + ni * 16 + l15;
          float a = acc[0][mi][ni][v], bb = acc[1][mi][ni][v];
          float sg = a / (1.f + __expf(-a));
          g[(size_t)(base + rt * 128 + row) * F_ + ft * 64 + col] = f2b(sg * bb);
        }
      }
}

// GEMM2: out[token] += rowwt * (g[slot,:] @ W2t[e]^T).  grid (64, 16, 8). 128x128, BK=32.
__global__ __launch_bounds__(256) void gemm2_kernel(
    const unsigned short* __restrict__ g, const unsigned short* __restrict__ w2t,
    const int* __restrict__ counts, const int* __restrict__ offs,
    const int* __restrict__ rowlist, const float* __restrict__ rowwt,
    float* __restrict__ out) {
  int e = blockIdx.z, nt = blockIdx.y, rt = blockIdx.x;
  int ne = counts[e];
  if (rt * 128 >= ne) return;
  int base = offs[e];

  __shared__ unsigned short aL[128 * 32];
  __shared__ unsigned short bL[128 * 32];
  __shared__ float rwL[128];
  __shared__ int   toL[128];

  int tid = threadIdx.x;
  int lane = tid & 63, wave = tid >> 6;
  int wm = (wave & 1) * 64, wn = (wave >> 1) * 64;
  int quad = lane >> 4, l15 = lane & 15;

  int srow = tid >> 2, kc = tid & 3;
  int r0c = min(rt * 128 + srow, ne - 1);
  int r1c = min(rt * 128 + 64 + srow, ne - 1);
  const unsigned short* ap0 = g + (size_t)(base + r0c) * F_ + kc * 8;
  const unsigned short* ap1 = g + (size_t)(base + r1c) * F_ + kc * 8;
  const unsigned short* bp0 = w2t + ((size_t)e * H_ + nt * 128 + srow) * F_ + kc * 8;
  const unsigned short* bp1 = bp0 + (size_t)64 * F_;

  unsigned short* aD0 = aL + wave * 512;
  unsigned short* aD1 = aL + 2048 + wave * 512;
  unsigned short* bD0 = bL + wave * 512;
  unsigned short* bD1 = bL + 2048 + wave * 512;

  if (tid < 128) {
    int rr = min(rt * 128 + tid, ne - 1);
    rwL[tid] = rowwt[base + rr];
    int tk = rowlist[base + rr];
    toL[tid] = ((tk & (S_ - 1)) * B_ + (tk >> 11)) * H_;
  }

  f32x4 acc[4][4];
#pragma unroll
  for (int i = 0; i < 4; i++)
    for (int j = 0; j < 4; j++) acc[i][j] = (f32x4){0.f, 0.f, 0.f, 0.f};

  for (int k0 = 0; k0 < F_; k0 += 32) {
    __syncthreads();
    gld16(ap0 + k0, aD0);
    gld16(ap1 + k0, aD1);
    gld16(bp0 + k0, bD0);
    gld16(bp1 + k0, bD1);
    __syncthreads();

    s16x8 af[4];
#pragma unroll
    for (int mi = 0; mi < 4; mi++)
      af[mi] = *(const s16x8*)&aL[(wm + mi * 16 + l15) * 32 + quad * 8];
    s16x8 bf[4];
#pragma unroll
    for (int ni = 0; ni < 4; ni++)
      bf[ni] = *(const s16x8*)&bL[(wn + ni * 16 + l15) * 32 + quad * 8];
#pragma unroll
    for (int mi = 0; mi < 4; mi++)
#pragma unroll
      for (int ni = 0; ni < 4; ni++)
        acc[mi][ni] = __builtin_amdgcn_mfma_f32_16x16x32_bf16(af[mi], bf[ni], acc[mi][ni], 0, 0, 0);
  }

#pragma unroll
  for (int mi = 0; mi < 4; mi++)
#pragma unroll
    for (int ni = 0; ni < 4; ni++)
#pragma unroll
      for (int v = 0; v < 4; v++) {
        int row = wm + mi * 16 + quad * 4 + v;
        if (rt * 128 + row < ne) {
          int col = wn + ni * 16 + l15;
          atomicAdd(&out[(size_t)toL[row] + nt * 128 + col], acc[mi][ni][v] * rwL[row]);
        }
      }
}

extern "C" void kernel_launch(void* const* d_in, const int* in_sizes, int n_in,
                              void* d_out, int out_size, void* d_ws, size_t ws_size,
                              hipStream_t stream) {
  const float* x  = (const float*)d_in[0];
  const float* wg = (const float*)d_in[1];
  const float* w1 = (const float*)d_in[2];
  const float* w2 = (const float*)d_in[3];
  float* out = (float*)d_out;

  char* ws = (char*)d_ws;
  int*   counts  = (int*)(ws + 0);
  int*   cursor  = (int*)(ws + 32);
  int*   offs    = (int*)(ws + 64);
  int*   eidx    = (int*)(ws + 128);
  float* ewt     = (float*)(ws + 65664);
  int*   rowlist = (int*)(ws + 131200);
  float* rowwt   = (float*)(ws + 196736);
  unsigned short* g   = (unsigned short*)(ws + 262272);
  unsigned short* xb  = (unsigned short*)(ws + 46399616);
  unsigned short* w1t = (unsigned short*)(ws + 79954048);
  unsigned short* w2t = (unsigned short*)(ws + 172228736);

  hipMemsetAsync(d_out, 0, (size_t)out_size * sizeof(float), stream);
  zero_kernel<<<1, 64, 0, stream>>>((int*)ws);
  cvt_kernel<<<T_ * H_ / 8 / 256, 256, 0, stream>>>(x, xb, T_ * H_ / 8);
  tcvt_kernel<<<dim3(F2_ / 64, H_ / 64, E_), 256, 0, stream>>>(w1, w1t, H_, F2_);
  tcvt_kernel<<<dim3(H_ / 64, F_ / 64, E_), 256, 0, stream>>>(w2, w2t, F_, H_);
  gate_kernel<<<T_ / 4, 256, 0, stream>>>(x, wg, counts, eidx, ewt);
  scan_kernel<<<1, 64, 0, stream>>>(counts, offs);
  assign_kernel<<<T_ / 256, 256, 0, stream>>>(eidx, ewt, offs, cursor, rowlist, rowwt);
  gemm1_kernel<<<dim3(64, 22, E_), 256, 0, stream>>>(xb, w1t, counts, offs, rowlist, g);
  gemm2_kernel<<<dim3(64, 16, E_), 256, 0, stream>>>(g, w2t, counts, offs, rowlist, rowwt, out);
}